// Round 1
// baseline (383.633 us; speedup 1.0000x reference)
//
#include <hip/hip_runtime.h>

// Fan Model nonlinear mixing.
// E: (1, 224, 12) fp32, A: (1, 12, 512, 512) fp32 -> out: (1, 224, 512, 512) fp32.
// Identity: sum_{i<j} E_i E_j a_i a_j = 0.5*((sum E_p a_p)^2 - sum E_p^2 a_p^2)
// => out[b,x] = L + 0.5*(L*L - Q), L = dot(E[b],a), Q = dot(E[b]^2, a^2).

#define NP 12
#define NB 224
#define HW (512 * 512)

__global__ void prep_e2(const float* __restrict__ E, float* __restrict__ E2, int n) {
    int i = blockIdx.x * blockDim.x + threadIdx.x;
    if (i < n) {
        float e = E[i];
        E2[i] = e * e;
    }
}

__global__ __launch_bounds__(256) void fan_mix(const float* __restrict__ E,
                                               const float* __restrict__ E2,
                                               const float* __restrict__ A,
                                               float* __restrict__ out) {
    const int x = blockIdx.x * blockDim.x + threadIdx.x;  // pixel index in [0, HW)

    // Per-pixel abundances and their squares, kept in registers.
    float a[NP], a2[NP];
#pragma unroll
    for (int p = 0; p < NP; ++p) {
        float v = A[(size_t)p * HW + x];  // coalesced: lane i -> consecutive addresses
        a[p] = v;
        a2[p] = v * v;
    }

    // E[b*NP+p] / E2[b*NP+p] are wave-uniform -> scalar loads via constant cache.
#pragma unroll 2
    for (int b = 0; b < NB; ++b) {
        float L = 0.0f, Q = 0.0f;
#pragma unroll
        for (int p = 0; p < NP; ++p) {
            L = fmaf(E[b * NP + p], a[p], L);
            Q = fmaf(E2[b * NP + p], a2[p], Q);
        }
        out[(size_t)b * HW + x] = L + 0.5f * (L * L - Q);  // coalesced dword store
    }
}

extern "C" void kernel_launch(void* const* d_in, const int* in_sizes, int n_in,
                              void* d_out, int out_size, void* d_ws, size_t ws_size,
                              hipStream_t stream) {
    const float* E = (const float*)d_in[0];   // (1, 224, 12)
    const float* A = (const float*)d_in[1];   // (1, 12, 512, 512)
    float* out = (float*)d_out;               // (1, 224, 512, 512)
    float* E2 = (float*)d_ws;                 // 224*12 floats scratch (re-poisoned each call)

    prep_e2<<<(NB * NP + 255) / 256, 256, 0, stream>>>(E, E2, NB * NP);
    fan_mix<<<HW / 256, 256, 0, stream>>>(E, E2, A, out);
}

// Round 3
// 242.274 us; speedup vs baseline: 1.5835x; 1.5835x over previous
//
#include <hip/hip_runtime.h>

// Fan Model nonlinear mixing.
// E: (1, 224, 12) fp32, A: (1, 12, 512, 512) fp32 -> out: (1, 224, 512, 512) fp32.
// Identity: sum_{i<j} E_i E_j a_i a_j = 0.5*((sum E_p a_p)^2 - sum E_p^2 a_p^2)
// => out[b,x] = L + 0.5*(L*L - Q), L = dot(E[b],a), Q = dot(E[b]^2, a^2).
//
// R3: same as R2 but with clang ext_vector_type for the nontemporal store
// (HIP_vector_type float2 is a class -> builtin rejects it).

#define NP 12
#define NB 224
#define HW (512 * 512)
#define BPG 28        // bands per group (NB / grid.y)
#define NGRP 8        // grid.y
#define BLOCK 256

typedef float vfloat2 __attribute__((ext_vector_type(2)));

__global__ void prep_e2(const float* __restrict__ E, float* __restrict__ E2, int n) {
    int i = blockIdx.x * blockDim.x + threadIdx.x;
    if (i < n) {
        float e = E[i];
        E2[i] = e * e;
    }
}

__global__ __launch_bounds__(BLOCK) void fan_mix(const float* __restrict__ E,
                                                 const float* __restrict__ E2,
                                                 const float* __restrict__ A,
                                                 float* __restrict__ out) {
    const int x2 = blockIdx.x * BLOCK + threadIdx.x;   // float2 (pixel-pair) index
    const int b0 = blockIdx.y * BPG;

    const vfloat2* __restrict__ A2v = (const vfloat2*)A;
    vfloat2* __restrict__ O2v = (vfloat2*)out;

    // Per-pixel-pair abundances and squares, in registers (~60 VGPR total).
    vfloat2 a[NP], a2[NP];
#pragma unroll
    for (int p = 0; p < NP; ++p) {
        vfloat2 v = A2v[(size_t)p * (HW / 2) + x2];    // coalesced dwordx2, 512 B/wave
        a[p] = v;
        a2[p] = v * v;
    }

#pragma unroll 2
    for (int b = b0; b < b0 + BPG; ++b) {
        float Lx = 0.f, Ly = 0.f, Qx = 0.f, Qy = 0.f;
#pragma unroll
        for (int p = 0; p < NP; ++p) {
            // E/E2 indices are wave-uniform -> scalar loads via constant cache.
            float e = E[b * NP + p];
            float e2 = E2[b * NP + p];
            Lx = fmaf(e, a[p].x, Lx);
            Ly = fmaf(e, a[p].y, Ly);
            Qx = fmaf(e2, a2[p].x, Qx);
            Qy = fmaf(e2, a2[p].y, Qy);
        }
        vfloat2 r;
        r.x = Lx + 0.5f * (Lx * Lx - Qx);
        r.y = Ly + 0.5f * (Ly * Ly - Qy);
        // Streaming store: out is write-once, never re-read -> nontemporal
        // keeps A resident in L2/L3.
        __builtin_nontemporal_store(r, &O2v[(size_t)b * (HW / 2) + x2]);
    }
}

extern "C" void kernel_launch(void* const* d_in, const int* in_sizes, int n_in,
                              void* d_out, int out_size, void* d_ws, size_t ws_size,
                              hipStream_t stream) {
    const float* E = (const float*)d_in[0];   // (1, 224, 12)
    const float* A = (const float*)d_in[1];   // (1, 12, 512, 512)
    float* out = (float*)d_out;               // (1, 224, 512, 512)
    float* E2 = (float*)d_ws;                 // 224*12 floats scratch

    prep_e2<<<(NB * NP + 255) / 256, 256, 0, stream>>>(E, E2, NB * NP);

    dim3 grid(HW / (2 * BLOCK), NGRP);        // (512, 8) = 4096 blocks
    fan_mix<<<grid, BLOCK, 0, stream>>>(E, E2, A, out);
}